// Round 11
// baseline (110.911 us; speedup 1.0000x reference)
//
#include <hip/hip_runtime.h>

// Conv2d 3x3 s1 p1 NCHW fp32: N=32, Cin=128, H=W=56, Cout=256.
// Round 11: m97-EXACT geometry. 128x128 tile, BK=32, 4 waves, wave-tile
//   64x64, LDS 32KB dbuf -> 3 blocks/CU co-resident (TLP hides barrier
//   drains, m97's mechanism: 37% MfmaUtil / 912 TF at this geometry).
//   Per wave K-step: 8 ds_read_b128 + 16 MFMA (m97 instruction profile).
//   LDS layout: 4 tile-rows per 256B LDS row, phys chunk = logical ^ (lr&15)
//   (4-bit XOR) -> frag reads ~2-way (free, m136); gll dest = tid*16 linear.
//   Ceiling model: 0.0457 B/FLOP -> 46% MfmaUtil ceiling (vs R10 tile's 30%).

typedef __attribute__((ext_vector_type(8))) short short8;
typedef __attribute__((ext_vector_type(4))) float float4v;

constexpr int NB = 32, CI = 128, HH = 56, WW = 56, CO = 256;
constexpr int HWP = HH * WW;                 // 3136
constexpr int HP = 58, WP = 58;              // padded spatial dims
constexpr size_t XTP_BYTES = (size_t)NB * HP * WP * CI * 2;   // 27,553,792
constexpr size_t WT_OFF    = XTP_BYTES;
constexpr size_t WT_BYTES  = (size_t)9 * CO * CI * 2;         // 589,824
constexpr size_t WS_NEED   = WT_OFF + WT_BYTES;

__device__ inline ushort f2bf(float v) {
    union { float f; uint u; } c; c.f = v;
    uint u = c.u;
    return (ushort)((u + 0x7fffu + ((u >> 16) & 1u)) >> 16);
}

__device__ inline void gll(const ushort* g, ushort* l) {
    __builtin_amdgcn_global_load_lds(
        (const __attribute__((address_space(1))) uint*)g,
        (__attribute__((address_space(3))) uint*)l, 16, 0, 0);
}

// ---- x: [n][ci][h][w] f32 -> xTp interior: [n][h+1][w+1][ci] bf16 ----
__global__ __launch_bounds__(256) void xform_x(const float* __restrict__ x,
                                               ushort* __restrict__ xTp) {
    int b = blockIdx.x;
    int cit = b & 3;
    int hwt = (b >> 2) % 49;
    int n   = b / (4 * 49);
    int ci0 = cit * 32, hw0 = hwt * 64;
    __shared__ float t[32][65];
    int tx = threadIdx.x;
    int col = tx & 63, r4 = tx >> 6;
#pragma unroll
    for (int rr = 0; rr < 8; ++rr) {
        int row = rr * 4 + r4;
        t[row][col] = x[((size_t)n * CI + ci0 + row) * HWP + hw0 + col];
    }
    __syncthreads();
    int i = tx & 31, j0 = tx >> 5;
#pragma unroll
    for (int jj = 0; jj < 8; ++jj) {
        int j = jj * 8 + j0;
        int hw = hw0 + j;
        int h = hw / WW, w = hw % WW;
        xTp[(((size_t)n * HP + h + 1) * WP + (w + 1)) * CI + ci0 + i] = f2bf(t[i][j]);
    }
}

// ---- zero-fill padded borders ----
__global__ __launch_bounds__(256) void xform_border(ushort* __restrict__ xTp) {
    int u = blockIdx.x * 256 + threadIdx.x;   // 116736 units of short8
    int ci8 = u & 15;
    int r = u >> 4;
    int n = r / 228, bb = r % 228;
    int hp, wp;
    if (bb < 58)       { hp = 0;  wp = bb; }
    else if (bb < 116) { hp = 57; wp = bb - 58; }
    else { int c = bb - 116; hp = 1 + (c >> 1); wp = (c & 1) * 57; }
    short8 z = (short8)0;
    *reinterpret_cast<short8*>(xTp + (((size_t)n * HP + hp) * WP + wp) * CI + ci8 * 8) = z;
}

// ---- w: [co][ci][kh][kw] f32 -> wT: [tap][co][ci] bf16 ----
__global__ __launch_bounds__(256) void xform_w(const float* __restrict__ w,
                                               ushort* __restrict__ wT) {
    int o = blockIdx.x * 256 + threadIdx.x;
    int ci = o & 127;
    int co = (o >> 7) & 255;
    int tap = o >> 15;
    wT[o] = f2bf(w[((size_t)co * CI + ci) * 9 + tap]);
}

// ---- main implicit GEMM: 128x128 tile, BK=32, 4 waves, 3 blocks/CU ----
__global__ __launch_bounds__(256, 3) void gemm_conv(
    const ushort* __restrict__ xTp, const ushort* __restrict__ wT,
    const float* __restrict__ bias, float* __restrict__ out)
{
    // per buffer: 32 LDS-rows x 128 elems (256B). Row lr holds tile-rows
    // 4lr..4lr+3 (each 32 k-elems = 4 chunks of 16B). phys chunk p at (lr,p)
    // holds logical q = p ^ (lr&15): tile-row = 4lr + (q>>2), k-chunk = q&3.
    __shared__ ushort As[2][32 * 128];   // 8KB x2 (weights: 128co x 32k)
    __shared__ ushort Bs[2][32 * 128];   // 8KB x2 (im2col : 128m  x 32k)

    // XCD swizzle: 1568 = 8 x 196; cblk pairs on same XCD (B-tile L2 share)
    int b = blockIdx.x;
    int logical = (b & 7) * 196 + (b >> 3);
    const int cblk = logical & 1;        // 0..1 (128 co each)
    const int mblk = logical >> 1;       // 0..783 (128 m each)

    const int tid = threadIdx.x, lane = tid & 63, wv = tid >> 6;  // 4 waves
    const int wr = wv >> 1;              // co-half (0..1) -> 64 co
    const int wc = wv & 1;               // m-half  (0..1) -> 64 m

    // ---- staging: 2 passes per operand; pass p: lr=(tid>>4)+16p, pc=tid&15
    // dest bytes = tid*16 + p*4096 (linear in tid ✓ gll-compatible)
    int aOff[2], bPix[2];
#pragma unroll
    for (int p = 0; p < 2; ++p) {
        int lr = (tid >> 4) + p * 16;
        int q  = (tid & 15) ^ (lr & 15);
        int tr = lr * 4 + (q >> 2);          // tile-row 0..127
        int kc8 = (q & 3) * 8;               // k-elem offset within 32-window
        aOff[p] = (cblk * 128 + tr) * CI + kc8;
        int m = mblk * 128 + tr;
        int n = m / HWP, hw = m % HWP, h = hw / WW, w = hw % WW;
        bPix[p] = ((n * HP + h + 1) * WP + (w + 1)) * CI + kc8;
    }
    const int dstE = (tid >> 4) * 128 + (tid & 15) * 8;   // + p*2048 elems

    // ---- fragment-read addresses (elems), one per 16-row sub-tile
    const int ln = lane & 15, ch = lane >> 4;   // ch = k-chunk 0..3
    int aAd[4], bAd[4];
#pragma unroll
    for (int f = 0; f < 4; ++f) {
        int lrA = wr * 16 + f * 4 + (ln >> 2);
        aAd[f] = lrA * 128 + ((((ln & 3) * 4 + ch) ^ (lrA & 15)) * 8);
        int lrB = wc * 16 + f * 4 + (ln >> 2);
        bAd[f] = lrB * 128 + ((((ln & 3) * 4 + ch) ^ (lrB & 15)) * 8);
    }

    float4v acc[4][4];
#pragma unroll
    for (int i = 0; i < 4; ++i)
#pragma unroll
        for (int j = 0; j < 4; ++j) acc[i][j] = (float4v)(0.0f);

    // K-step t (0..35): tap = t>>2, kq = t&3 (32-elem quarter of 128 ci)
    auto STAGE = [&](int buf, int t) {
        int tap = t >> 2, kq = (t & 3) * 32;
        int ao = tap * (CO * CI) + kq;
        int dh = tap / 3 - 1, dw = tap % 3 - 1;
        int bo = (dh * WP + dw) * CI + kq;
#pragma unroll
        for (int p = 0; p < 2; ++p) {
            gll(wT + aOff[p] + ao, &As[buf][dstE + p * 2048]);
            gll(xTp + bPix[p] + bo, &Bs[buf][dstE + p * 2048]);
        }
    };

    auto COMPUTE = [&](int buf) {
        short8 aF[4], bF[4];
#pragma unroll
        for (int f = 0; f < 4; ++f) {
            aF[f] = *(const short8*)(&As[buf][aAd[f]]);
            bF[f] = *(const short8*)(&Bs[buf][bAd[f]]);
        }
        __builtin_amdgcn_s_setprio(1);
#pragma unroll
        for (int fi = 0; fi < 4; ++fi)
#pragma unroll
            for (int gi = 0; gi < 4; ++gi)
                acc[fi][gi] = __builtin_amdgcn_mfma_f32_16x16x32_bf16(
                    aF[fi], bF[gi], acc[fi][gi], 0, 0, 0);
        __builtin_amdgcn_s_setprio(0);
    };

    // m97 2-barrier dbuf loop: cross-block TLP (3/CU) hides the drains
    STAGE(0, 0);
    __syncthreads();
#pragma unroll 1
    for (int t = 0; t < 36; ++t) {
        const int cur = t & 1;
        if (t + 1 < 36) STAGE(cur ^ 1, t + 1);
        COMPUTE(cur);
        __syncthreads();
    }

    // epilogue: C[co][m] + bias -> out[n][co][h][w] (scalar, 1.2x amp)
    const int co0 = cblk * 128 + wr * 64;
    const int m0  = mblk * 128 + wc * 64;
    float bv[4][4];
#pragma unroll
    for (int f = 0; f < 4; ++f)
#pragma unroll
        for (int r = 0; r < 4; ++r)
            bv[f][r] = bias[co0 + f * 16 + (lane >> 4) * 4 + r];
#pragma unroll
    for (int g = 0; g < 4; ++g) {
        int m = m0 + g * 16 + (lane & 15);
        int n = m / HWP, hw = m % HWP;
        float* obase = out + (size_t)n * CO * HWP + hw;
#pragma unroll
        for (int f = 0; f < 4; ++f) {
            int co = co0 + f * 16 + (lane >> 4) * 4;
#pragma unroll
            for (int r = 0; r < 4; ++r)
                obase[(size_t)(co + r) * HWP] = acc[f][g][r] + bv[f][r];
        }
    }
}

// ---- fallback (round-1 direct conv) if ws too small ----
__global__ __launch_bounds__(256) void conv_k(
    const float* __restrict__ x, const float* __restrict__ wgt,
    const float* __restrict__ bias, float* __restrict__ out)
{
    int idx = blockIdx.x * 256 + threadIdx.x;
    int wg = idx % 14; int t = idx / 14;
    int ho = t % 56; t /= 56;
    int cog = t % 64; int n = t / 64;
    int w0 = wg * 4, co0 = cog * 4;
    float acc[4][4];
#pragma unroll
    for (int j = 0; j < 4; ++j) {
        float bj = bias[co0 + j];
#pragma unroll
        for (int p = 0; p < 4; ++p) acc[j][p] = bj;
    }
    const float* xn = x + (size_t)n * CI * HWP;
    for (int ci = 0; ci < CI; ++ci) {
        float xr[3][6];
#pragma unroll
        for (int kh = 0; kh < 3; ++kh) {
            int hi = ho + kh - 1;
            if (hi >= 0 && hi < HH) {
                const float* row = xn + ((size_t)ci * HH + hi) * WW;
                float4 cc = *reinterpret_cast<const float4*>(row + w0);
                xr[kh][1] = cc.x; xr[kh][2] = cc.y; xr[kh][3] = cc.z; xr[kh][4] = cc.w;
                xr[kh][0] = (w0 > 0) ? row[w0 - 1] : 0.0f;
                xr[kh][5] = (w0 + 4 < WW) ? row[w0 + 4] : 0.0f;
            } else {
#pragma unroll
                for (int q = 0; q < 6; ++q) xr[kh][q] = 0.0f;
            }
        }
#pragma unroll
        for (int j = 0; j < 4; ++j) {
            const float* wp = wgt + ((size_t)(co0 + j) * CI + ci) * 9;
            float wvv[9];
#pragma unroll
            for (int q = 0; q < 9; ++q) wvv[q] = wp[q];
#pragma unroll
            for (int kh = 0; kh < 3; ++kh)
#pragma unroll
                for (int kw = 0; kw < 3; ++kw)
#pragma unroll
                    for (int p = 0; p < 4; ++p)
                        acc[j][p] = fmaf(xr[kh][p + kw], wvv[kh * 3 + kw], acc[j][p]);
        }
    }
#pragma unroll
    for (int j = 0; j < 4; ++j) {
        float4 v = make_float4(acc[j][0], acc[j][1], acc[j][2], acc[j][3]);
        *reinterpret_cast<float4*>(out + (((size_t)n * CO + co0 + j) * HH + ho) * WW + w0) = v;
    }
}

extern "C" void kernel_launch(void* const* d_in, const int* in_sizes, int n_in,
                              void* d_out, int out_size, void* d_ws, size_t ws_size,
                              hipStream_t stream) {
    const float* x = (const float*)d_in[0];
    const float* w = (const float*)d_in[1];
    const float* b = (const float*)d_in[2];
    float* out = (float*)d_out;

    if (ws_size < WS_NEED) {  // safety fallback
        hipLaunchKernelGGL(conv_k, dim3(6272), dim3(256), 0, stream, x, w, b, out);
        return;
    }

    ushort* xTp = (ushort*)d_ws;
    ushort* wT  = (ushort*)((char*)d_ws + WT_OFF);

    hipLaunchKernelGGL(xform_x, dim3(32 * 49 * 4), dim3(256), 0, stream, x, xTp);
    hipLaunchKernelGGL(xform_border, dim3(456), dim3(256), 0, stream, xTp);
    hipLaunchKernelGGL(xform_w, dim3(9 * CO * CI / 256), dim3(256), 0, stream, w, wT);
    hipLaunchKernelGGL(gemm_conv, dim3(1568), dim3(256), 0, stream,
                       xTp, wT, b, out);
}

// Round 12
// 88.384 us; speedup vs baseline: 1.2549x; 1.2549x over previous
//
#include <hip/hip_runtime.h>

// Conv2d 3x3 s1 p1 NCHW fp32: N=32, Cin=128, H=W=56, Cout=256.
// Round 12: R7 schedule with BN=224 (grid 448 = 8x56 -> 87.5% tail vs 76.6%).
//   BM=256, BN=224 (= 4 image rows, uniform n per block), BK=64, 18 K-tiles,
//   8 waves as 4co x 2m (wave-tile 64x112, acc[4][7]=112 AGPR).
//   LDS 120KB: As[2][256][64] 32KBx2 + Bs[2][224][64] 28KBx2.
//   B staged in 3.5 passes of 512x16B (pass 3 masked to waves 0-3); vmcnt(4)
//   boundary audited for both wave groups (drains t+1 fully, keeps t+2 h0).
//   LDS layout: 128B rows, chunk ^= (row&7) -- the ONLY verified-0-conflict
//   family (R11's 256B-row 4-bit variant: 7.2M conflicts. reverted).
//   Phases per R7 (best measured, 86.4us GEMM): 5 barriers/tile, MMQ order
//   (0,q0)(0,q1)(1,q1)(1,q0), bQ0 register-held, counted vmcnt.

typedef __attribute__((ext_vector_type(8))) short short8;
typedef __attribute__((ext_vector_type(4))) float float4v;

constexpr int NB = 32, CI = 128, HH = 56, WW = 56, CO = 256;
constexpr int HWP = HH * WW;                 // 3136
constexpr int HP = 58, WP = 58;              // padded spatial dims
constexpr size_t XTP_BYTES = (size_t)NB * HP * WP * CI * 2;   // 27,553,792
constexpr size_t WT_OFF    = XTP_BYTES;
constexpr size_t WT_BYTES  = (size_t)9 * CO * CI * 2;         // 589,824
constexpr size_t WS_NEED   = WT_OFF + WT_BYTES;

__device__ inline ushort f2bf(float v) {
    union { float f; uint u; } c; c.f = v;
    uint u = c.u;
    return (ushort)((u + 0x7fffu + ((u >> 16) & 1u)) >> 16);
}

__device__ inline void gll(const ushort* g, ushort* l) {
    __builtin_amdgcn_global_load_lds(
        (const __attribute__((address_space(1))) uint*)g,
        (__attribute__((address_space(3))) uint*)l, 16, 0, 0);
}

#define BAR() do { asm volatile("" ::: "memory"); \
                   __builtin_amdgcn_s_barrier(); \
                   asm volatile("" ::: "memory"); } while (0)

// ---- x: [n][ci][h][w] f32 -> xTp interior: [n][h+1][w+1][ci] bf16 ----
__global__ __launch_bounds__(256) void xform_x(const float* __restrict__ x,
                                               ushort* __restrict__ xTp) {
    int b = blockIdx.x;
    int cit = b & 3;
    int hwt = (b >> 2) % 49;
    int n   = b / (4 * 49);
    int ci0 = cit * 32, hw0 = hwt * 64;
    __shared__ float t[32][65];
    int tx = threadIdx.x;
    int col = tx & 63, r4 = tx >> 6;
#pragma unroll
    for (int rr = 0; rr < 8; ++rr) {
        int row = rr * 4 + r4;
        t[row][col] = x[((size_t)n * CI + ci0 + row) * HWP + hw0 + col];
    }
    __syncthreads();
    int i = tx & 31, j0 = tx >> 5;
#pragma unroll
    for (int jj = 0; jj < 8; ++jj) {
        int j = jj * 8 + j0;
        int hw = hw0 + j;
        int h = hw / WW, w = hw % WW;
        xTp[(((size_t)n * HP + h + 1) * WP + (w + 1)) * CI + ci0 + i] = f2bf(t[i][j]);
    }
}

// ---- zero-fill padded borders ----
__global__ __launch_bounds__(256) void xform_border(ushort* __restrict__ xTp) {
    int u = blockIdx.x * 256 + threadIdx.x;   // 116736 units of short8
    int ci8 = u & 15;
    int r = u >> 4;
    int n = r / 228, bb = r % 228;
    int hp, wp;
    if (bb < 58)       { hp = 0;  wp = bb; }
    else if (bb < 116) { hp = 57; wp = bb - 58; }
    else { int c = bb - 116; hp = 1 + (c >> 1); wp = (c & 1) * 57; }
    short8 z = (short8)0;
    *reinterpret_cast<short8*>(xTp + (((size_t)n * HP + hp) * WP + wp) * CI + ci8 * 8) = z;
}

// ---- w: [co][ci][kh][kw] f32 -> wT: [tap][co][ci] bf16 ----
__global__ __launch_bounds__(256) void xform_w(const float* __restrict__ w,
                                               ushort* __restrict__ wT) {
    int o = blockIdx.x * 256 + threadIdx.x;
    int ci = o & 127;
    int co = (o >> 7) & 255;
    int tap = o >> 15;
    wT[o] = f2bf(w[((size_t)co * CI + ci) * 9 + tap]);
}

// ---- main implicit GEMM: 256co x 224m tile, R7 schedule ----
__global__ __launch_bounds__(512, 2) void gemm_conv(
    const ushort* __restrict__ xTp, const ushort* __restrict__ wT,
    const float* __restrict__ bias, float* __restrict__ out)
{
    __shared__ ushort As[2][256 * 64];   // 32KB x2 (weights: co x k)
    __shared__ ushort Bs[2][224 * 64];   // 28KB x2 (im2col : m  x k)

    // XCD swizzle: 448 = 8 x 56, bijective
    int b = blockIdx.x;
    const int mblk = (b & 7) * 56 + (b >> 3);

    const int tid = threadIdx.x, lane = tid & 63, wv = tid >> 6;  // 8 waves
    const int wr = wv >> 1;          // co-quarter (0..3) -> 64 co rows
    const int wc = wv & 1;           // m-half     (0..1) -> 112 m cols

    // staging addressing (128B LDS rows, 8 thr/row, chunk ^= row&7)
    const int s8 = (((tid & 7) ^ ((tid >> 3) & 7))) * 8;
    const int aSrc = (tid >> 3) * CI + s8;
    const int dstOff = (tid >> 3) * 64 + (tid & 7) * 8;

    // m-tile = 4 rows of image nimg, rows h0..h0+3 (uniform per block)
    const int nimg = mblk / 14;
    const int h0   = (mblk % 14) * 4;
    int bPix[4];   // B staging pass p -> lds row p*64+(tid>>3)
#pragma unroll
    for (int p = 0; p < 4; ++p) {
        int row = p * 64 + (tid >> 3);           // 0..255 (p=3 used by tid<256)
        int hh = h0 + row / 56, ww2 = row % 56;  // hh <= h0+4 <= 56 in padded bounds
        bPix[p] = ((nimg * HP + hh + 1) * WP + (ww2 + 1)) * CI + s8;
    }

    // fragment-read addressing (row&7 == lane&7 since bases % 8 == 0)
    const int ck0 = (((lane >> 4)) ^ (lane & 7)) * 8;
    const int ck1 = ((4 + (lane >> 4)) ^ (lane & 7)) * 8;
    const int aRowOff = (wr * 64 + (lane & 15)) * 64;    // + qr*2048 + fi*1024
    const int bRowOff = (wc * 112 + (lane & 15)) * 64;   // + gi*1024

    float4v acc[4][7];   // [fi 0..3 co-frags][gi 0..6 m-frags] = 112 regs
#pragma unroll
    for (int i = 0; i < 4; ++i)
#pragma unroll
        for (int j = 0; j < 7; ++j) acc[i][j] = (float4v)(0.0f);

    short8 aF[2][2];     // current qr-half A frags
    short8 bQ0[4][2];    // B gi 0..3 (held ph1..ph4)
    short8 bQ1[3][2];    // B gi 4..6 (held ph2..ph3)

    auto STAGE_A = [&](int buf, int t, int h) {
        int tap = t >> 1, kh = (t & 1) * 64;
        const ushort* src = wT + aSrc + tap * (CO * CI) + kh + h * 16384;
        ushort* dst = &As[buf][h * 8192 + dstOff];
        gll(src, dst);
        gll(src + 8192, dst + 4096);
    };
    auto STAGE_B = [&](int buf, int t, int h) {
        int tap = t >> 1, kh = (t & 1) * 64;
        int dh = tap / 3 - 1, dw = tap % 3 - 1;
        int toff = (dh * WP + dw) * CI + kh;
        ushort* dst = &Bs[buf][h * 8192 + dstOff];
        if (h == 0) {
            gll(xTp + bPix[0] + toff, dst);
            gll(xTp + bPix[1] + toff, dst + 4096);
        } else {
            gll(xTp + bPix[2] + toff, dst);
            if (tid < 256) gll(xTp + bPix[3] + toff, dst + 4096);  // rows 192..223
        }
    };
    auto LDA = [&](int buf, int qr) {
        const ushort* p = &As[buf][aRowOff + qr * 2048];
#pragma unroll
        for (int fi = 0; fi < 2; ++fi) {
            aF[fi][0] = *(const short8*)(p + fi * 1024 + ck0);
            aF[fi][1] = *(const short8*)(p + fi * 1024 + ck1);
        }
    };
    auto LDB0 = [&](int buf) {
        const ushort* p = &Bs[buf][bRowOff];
#pragma unroll
        for (int gi = 0; gi < 4; ++gi) {
            bQ0[gi][0] = *(const short8*)(p + gi * 1024 + ck0);
            bQ0[gi][1] = *(const short8*)(p + gi * 1024 + ck1);
        }
    };
    auto LDB1 = [&](int buf) {
        const ushort* p = &Bs[buf][bRowOff + 4096];
#pragma unroll
        for (int gi = 0; gi < 3; ++gi) {
            bQ1[gi][0] = *(const short8*)(p + gi * 1024 + ck0);
            bQ1[gi][1] = *(const short8*)(p + gi * 1024 + ck1);
        }
    };

#define MMQ0(QR) do { \
    __builtin_amdgcn_s_setprio(1); \
    _Pragma("unroll") \
    for (int kc = 0; kc < 2; ++kc) \
        _Pragma("unroll") \
        for (int fi = 0; fi < 2; ++fi) \
            _Pragma("unroll") \
            for (int gi = 0; gi < 4; ++gi) \
                acc[(QR)*2+fi][gi] = __builtin_amdgcn_mfma_f32_16x16x32_bf16( \
                    aF[fi][kc], bQ0[gi][kc], acc[(QR)*2+fi][gi], 0, 0, 0); \
    __builtin_amdgcn_s_setprio(0); \
} while (0)
#define MMQ1(QR) do { \
    __builtin_amdgcn_s_setprio(1); \
    _Pragma("unroll") \
    for (int kc = 0; kc < 2; ++kc) \
        _Pragma("unroll") \
        for (int fi = 0; fi < 2; ++fi) \
            _Pragma("unroll") \
            for (int gi = 0; gi < 3; ++gi) \
                acc[(QR)*2+fi][4+gi] = __builtin_amdgcn_mfma_f32_16x16x32_bf16( \
                    aF[fi][kc], bQ1[gi][kc], acc[(QR)*2+fi][4+gi], 0, 0, 0); \
    __builtin_amdgcn_s_setprio(0); \
} while (0)

    // One K-tile, R7's exact 5-barrier schedule
    auto TILE = [&](int c, int t) {
        LDA(c, 0);
        LDB0(c);
        if (t + 1 < 18) STAGE_A(c ^ 1, t + 1, 1);
        BAR();
        MMQ0(0);
        LDB1(c);
        if (t + 1 < 18) STAGE_B(c ^ 1, t + 1, 1);
        BAR();
        MMQ1(0);
        LDA(c, 1);
        if (t + 2 < 18) STAGE_B(c, t + 2, 0);
        BAR();
        MMQ1(1);
        if (t + 2 < 18) STAGE_A(c, t + 2, 0);
        BAR();
        MMQ0(1);
        if (t <= 15)      { asm volatile("s_waitcnt vmcnt(4)" ::: "memory"); }
        else if (t == 16) { asm volatile("s_waitcnt vmcnt(0)" ::: "memory"); }
        BAR();
    };

    // prologue: tile0 (4 halves) + B-h0(1), A-h0(1)
    STAGE_A(0, 0, 0); STAGE_A(0, 0, 1);
    STAGE_B(0, 0, 0); STAGE_B(0, 0, 1);
    STAGE_B(1, 1, 0); STAGE_A(1, 1, 0);
    asm volatile("s_waitcnt vmcnt(4)" ::: "memory");
    BAR();

#pragma unroll 1
    for (int tp = 0; tp < 18; tp += 2) {   // 9 pairs, static buffer parity
        TILE(0, tp);
        TILE(1, tp + 1);
    }
#undef MMQ0
#undef MMQ1

    // epilogue: C[co][m] + bias -> out[nimg][co][h][w] (scalar, 1.2x amp)
    const int co0 = wr * 64;
    const int m0  = mblk * 224 + wc * 112;
    float bv[4][4];
#pragma unroll
    for (int f = 0; f < 4; ++f)
#pragma unroll
        for (int r = 0; r < 4; ++r)
            bv[f][r] = bias[co0 + f * 16 + (lane >> 4) * 4 + r];
#pragma unroll
    for (int g = 0; g < 7; ++g) {
        int m = m0 + g * 16 + (lane & 15);
        int hw = m - nimg * HWP;
        float* obase = out + (size_t)nimg * CO * HWP + hw;
#pragma unroll
        for (int f = 0; f < 4; ++f) {
            int co = co0 + f * 16 + (lane >> 4) * 4;
#pragma unroll
            for (int r = 0; r < 4; ++r)
                obase[(size_t)(co + r) * HWP] = acc[f][g][r] + bv[f][r];
        }
    }
}

// ---- fallback (round-1 direct conv) if ws too small ----
__global__ __launch_bounds__(256) void conv_k(
    const float* __restrict__ x, const float* __restrict__ wgt,
    const float* __restrict__ bias, float* __restrict__ out)
{
    int idx = blockIdx.x * 256 + threadIdx.x;
    int wg = idx % 14; int t = idx / 14;
    int ho = t % 56; t /= 56;
    int cog = t % 64; int n = t / 64;
    int w0 = wg * 4, co0 = cog * 4;
    float acc[4][4];
#pragma unroll
    for (int j = 0; j < 4; ++j) {
        float bj = bias[co0 + j];
#pragma unroll
        for (int p = 0; p < 4; ++p) acc[j][p] = bj;
    }
    const float* xn = x + (size_t)n * CI * HWP;
    for (int ci = 0; ci < CI; ++ci) {
        float xr[3][6];
#pragma unroll
        for (int kh = 0; kh < 3; ++kh) {
            int hi = ho + kh - 1;
            if (hi >= 0 && hi < HH) {
                const float* row = xn + ((size_t)ci * HH + hi) * WW;
                float4 cc = *reinterpret_cast<const float4*>(row + w0);
                xr[kh][1] = cc.x; xr[kh][2] = cc.y; xr[kh][3] = cc.z; xr[kh][4] = cc.w;
                xr[kh][0] = (w0 > 0) ? row[w0 - 1] : 0.0f;
                xr[kh][5] = (w0 + 4 < WW) ? row[w0 + 4] : 0.0f;
            } else {
#pragma unroll
                for (int q = 0; q < 6; ++q) xr[kh][q] = 0.0f;
            }
        }
#pragma unroll
        for (int j = 0; j < 4; ++j) {
            const float* wp = wgt + ((size_t)(co0 + j) * CI + ci) * 9;
            float wvv[9];
#pragma unroll
            for (int q = 0; q < 9; ++q) wvv[q] = wp[q];
#pragma unroll
            for (int kh = 0; kh < 3; ++kh)
#pragma unroll
                for (int kw = 0; kw < 3; ++kw)
#pragma unroll
                    for (int p = 0; p < 4; ++p)
                        acc[j][p] = fmaf(xr[kh][p + kw], wvv[kh * 3 + kw], acc[j][p]);
        }
    }
#pragma unroll
    for (int j = 0; j < 4; ++j) {
        float4 v = make_float4(acc[j][0], acc[j][1], acc[j][2], acc[j][3]);
        *reinterpret_cast<float4*>(out + (((size_t)n * CO + co0 + j) * HH + ho) * WW + w0) = v;
    }
}

extern "C" void kernel_launch(void* const* d_in, const int* in_sizes, int n_in,
                              void* d_out, int out_size, void* d_ws, size_t ws_size,
                              hipStream_t stream) {
    const float* x = (const float*)d_in[0];
    const float* w = (const float*)d_in[1];
    const float* b = (const float*)d_in[2];
    float* out = (float*)d_out;

    if (ws_size < WS_NEED) {  // safety fallback
        hipLaunchKernelGGL(conv_k, dim3(6272), dim3(256), 0, stream, x, w, b, out);
        return;
    }

    ushort* xTp = (ushort*)d_ws;
    ushort* wT  = (ushort*)((char*)d_ws + WT_OFF);

    hipLaunchKernelGGL(xform_x, dim3(32 * 49 * 4), dim3(256), 0, stream, x, xTp);
    hipLaunchKernelGGL(xform_border, dim3(456), dim3(256), 0, stream, xTp);
    hipLaunchKernelGGL(xform_w, dim3(9 * CO * CI / 256), dim3(256), 0, stream, w, wT);
    hipLaunchKernelGGL(gemm_conv, dim3(448), dim3(512), 0, stream,
                       xTp, wT, b, out);
}

// Round 13
// 83.955 us; speedup vs baseline: 1.3211x; 1.0528x over previous
//
#include <hip/hip_runtime.h>

// Conv2d 3x3 s1 p1 NCHW fp32: N=32, Cin=128, H=W=56, Cout=256.
// Round 13: R12 (BM=256 x BN=224, 87.5% tail, best measured) with:
//   (a) boundary barrier merged into ph4 -> 4 barriers/tile.
//       vmcnt-queue replay: at tile-t ph4, outstanding = t+1.h0(4) t+1.h1(4)
//       t+2.h0(4); vmcnt(4) drains t+1 fully, keeps t+2.h0 in flight;
//       invariant reproduces at each tile entry. All LDS WAR distances >=2
//       barriers.  (b) xform_border + xform_w fused into one aux kernel.
//   Everything else identical to R12 (proven: 0 conflicts, absmax 0.03125).

typedef __attribute__((ext_vector_type(8))) short short8;
typedef __attribute__((ext_vector_type(4))) float float4v;

constexpr int NB = 32, CI = 128, HH = 56, WW = 56, CO = 256;
constexpr int HWP = HH * WW;                 // 3136
constexpr int HP = 58, WP = 58;              // padded spatial dims
constexpr size_t XTP_BYTES = (size_t)NB * HP * WP * CI * 2;   // 27,553,792
constexpr size_t WT_OFF    = XTP_BYTES;
constexpr size_t WT_BYTES  = (size_t)9 * CO * CI * 2;         // 589,824
constexpr size_t WS_NEED   = WT_OFF + WT_BYTES;

__device__ inline ushort f2bf(float v) {
    union { float f; uint u; } c; c.f = v;
    uint u = c.u;
    return (ushort)((u + 0x7fffu + ((u >> 16) & 1u)) >> 16);
}

__device__ inline void gll(const ushort* g, ushort* l) {
    __builtin_amdgcn_global_load_lds(
        (const __attribute__((address_space(1))) uint*)g,
        (__attribute__((address_space(3))) uint*)l, 16, 0, 0);
}

#define BAR() do { asm volatile("" ::: "memory"); \
                   __builtin_amdgcn_s_barrier(); \
                   asm volatile("" ::: "memory"); } while (0)

// ---- x: [n][ci][h][w] f32 -> xTp interior: [n][h+1][w+1][ci] bf16 ----
__global__ __launch_bounds__(256) void xform_x(const float* __restrict__ x,
                                               ushort* __restrict__ xTp) {
    int b = blockIdx.x;
    int cit = b & 3;
    int hwt = (b >> 2) % 49;
    int n   = b / (4 * 49);
    int ci0 = cit * 32, hw0 = hwt * 64;
    __shared__ float t[32][65];
    int tx = threadIdx.x;
    int col = tx & 63, r4 = tx >> 6;
#pragma unroll
    for (int rr = 0; rr < 8; ++rr) {
        int row = rr * 4 + r4;
        t[row][col] = x[((size_t)n * CI + ci0 + row) * HWP + hw0 + col];
    }
    __syncthreads();
    int i = tx & 31, j0 = tx >> 5;
#pragma unroll
    for (int jj = 0; jj < 8; ++jj) {
        int j = jj * 8 + j0;
        int hw = hw0 + j;
        int h = hw / WW, w = hw % WW;
        xTp[(((size_t)n * HP + h + 1) * WP + (w + 1)) * CI + ci0 + i] = f2bf(t[i][j]);
    }
}

// ---- fused aux: blocks [0,1152): w -> wT [tap][co][ci]; [1152,1608): borders ----
__global__ __launch_bounds__(256) void xform_aux(const float* __restrict__ w,
                                                 ushort* __restrict__ wT,
                                                 ushort* __restrict__ xTp) {
    int bb = blockIdx.x;
    if (bb < 1152) {
        int o = bb * 256 + threadIdx.x;       // 294912 total
        int ci = o & 127;
        int co = (o >> 7) & 255;
        int tap = o >> 15;
        wT[o] = f2bf(w[((size_t)co * CI + ci) * 9 + tap]);
    } else {
        int u = (bb - 1152) * 256 + threadIdx.x;  // 116736 units of short8
        int ci8 = u & 15;
        int r = u >> 4;
        int n = r / 228, bc = r % 228;
        int hp, wp;
        if (bc < 58)       { hp = 0;  wp = bc; }
        else if (bc < 116) { hp = 57; wp = bc - 58; }
        else { int c = bc - 116; hp = 1 + (c >> 1); wp = (c & 1) * 57; }
        short8 z = (short8)0;
        *reinterpret_cast<short8*>(xTp + (((size_t)n * HP + hp) * WP + wp) * CI + ci8 * 8) = z;
    }
}

// ---- main implicit GEMM: 256co x 224m tile, 4 barriers/tile ----
__global__ __launch_bounds__(512, 2) void gemm_conv(
    const ushort* __restrict__ xTp, const ushort* __restrict__ wT,
    const float* __restrict__ bias, float* __restrict__ out)
{
    __shared__ ushort As[2][256 * 64];   // 32KB x2 (weights: co x k)
    __shared__ ushort Bs[2][224 * 64];   // 28KB x2 (im2col : m  x k)

    // XCD swizzle: 448 = 8 x 56, bijective
    int b = blockIdx.x;
    const int mblk = (b & 7) * 56 + (b >> 3);

    const int tid = threadIdx.x, lane = tid & 63, wv = tid >> 6;  // 8 waves
    const int wr = wv >> 1;          // co-quarter (0..3) -> 64 co rows
    const int wc = wv & 1;           // m-half     (0..1) -> 112 m cols

    // staging addressing (128B LDS rows, 8 thr/row, chunk ^= row&7)
    const int s8 = (((tid & 7) ^ ((tid >> 3) & 7))) * 8;
    const int aSrc = (tid >> 3) * CI + s8;
    const int dstOff = (tid >> 3) * 64 + (tid & 7) * 8;

    // m-tile = 4 rows of image nimg, rows h0..h0+3 (uniform per block)
    const int nimg = mblk / 14;
    const int h0   = (mblk % 14) * 4;
    int bPix[4];   // B staging pass p -> lds row p*64+(tid>>3)
#pragma unroll
    for (int p = 0; p < 4; ++p) {
        int row = p * 64 + (tid >> 3);           // 0..255 (p=3 used by tid<256)
        int hh = h0 + row / 56, ww2 = row % 56;
        bPix[p] = ((nimg * HP + hh + 1) * WP + (ww2 + 1)) * CI + s8;
    }

    // fragment-read addressing
    const int ck0 = (((lane >> 4)) ^ (lane & 7)) * 8;
    const int ck1 = ((4 + (lane >> 4)) ^ (lane & 7)) * 8;
    const int aRowOff = (wr * 64 + (lane & 15)) * 64;    // + qr*2048 + fi*1024
    const int bRowOff = (wc * 112 + (lane & 15)) * 64;   // + gi*1024

    float4v acc[4][7];   // 112 acc regs
#pragma unroll
    for (int i = 0; i < 4; ++i)
#pragma unroll
        for (int j = 0; j < 7; ++j) acc[i][j] = (float4v)(0.0f);

    short8 aF[2][2];
    short8 bQ0[4][2];    // B gi 0..3 (held ph1..ph4)
    short8 bQ1[3][2];    // B gi 4..6 (held ph2..ph3)

    auto STAGE_A = [&](int buf, int t, int h) {
        int tap = t >> 1, kh = (t & 1) * 64;
        const ushort* src = wT + aSrc + tap * (CO * CI) + kh + h * 16384;
        ushort* dst = &As[buf][h * 8192 + dstOff];
        gll(src, dst);
        gll(src + 8192, dst + 4096);
    };
    auto STAGE_B = [&](int buf, int t, int h) {
        int tap = t >> 1, kh = (t & 1) * 64;
        int dh = tap / 3 - 1, dw = tap % 3 - 1;
        int toff = (dh * WP + dw) * CI + kh;
        ushort* dst = &Bs[buf][h * 8192 + dstOff];
        if (h == 0) {
            gll(xTp + bPix[0] + toff, dst);
            gll(xTp + bPix[1] + toff, dst + 4096);
        } else {
            gll(xTp + bPix[2] + toff, dst);
            if (tid < 256) gll(xTp + bPix[3] + toff, dst + 4096);
        }
    };
    auto LDA = [&](int buf, int qr) {
        const ushort* p = &As[buf][aRowOff + qr * 2048];
#pragma unroll
        for (int fi = 0; fi < 2; ++fi) {
            aF[fi][0] = *(const short8*)(p + fi * 1024 + ck0);
            aF[fi][1] = *(const short8*)(p + fi * 1024 + ck1);
        }
    };
    auto LDB0 = [&](int buf) {
        const ushort* p = &Bs[buf][bRowOff];
#pragma unroll
        for (int gi = 0; gi < 4; ++gi) {
            bQ0[gi][0] = *(const short8*)(p + gi * 1024 + ck0);
            bQ0[gi][1] = *(const short8*)(p + gi * 1024 + ck1);
        }
    };
    auto LDB1 = [&](int buf) {
        const ushort* p = &Bs[buf][bRowOff + 4096];
#pragma unroll
        for (int gi = 0; gi < 3; ++gi) {
            bQ1[gi][0] = *(const short8*)(p + gi * 1024 + ck0);
            bQ1[gi][1] = *(const short8*)(p + gi * 1024 + ck1);
        }
    };

#define MMQ0(QR) do { \
    __builtin_amdgcn_s_setprio(1); \
    _Pragma("unroll") \
    for (int kc = 0; kc < 2; ++kc) \
        _Pragma("unroll") \
        for (int fi = 0; fi < 2; ++fi) \
            _Pragma("unroll") \
            for (int gi = 0; gi < 4; ++gi) \
                acc[(QR)*2+fi][gi] = __builtin_amdgcn_mfma_f32_16x16x32_bf16( \
                    aF[fi][kc], bQ0[gi][kc], acc[(QR)*2+fi][gi], 0, 0, 0); \
    __builtin_amdgcn_s_setprio(0); \
} while (0)
#define MMQ1(QR) do { \
    __builtin_amdgcn_s_setprio(1); \
    _Pragma("unroll") \
    for (int kc = 0; kc < 2; ++kc) \
        _Pragma("unroll") \
        for (int fi = 0; fi < 2; ++fi) \
            _Pragma("unroll") \
            for (int gi = 0; gi < 3; ++gi) \
                acc[(QR)*2+fi][4+gi] = __builtin_amdgcn_mfma_f32_16x16x32_bf16( \
                    aF[fi][kc], bQ1[gi][kc], acc[(QR)*2+fi][4+gi], 0, 0, 0); \
    __builtin_amdgcn_s_setprio(0); \
} while (0)

    // One K-tile, 4 barriers (boundary vmcnt merged into ph4's barrier)
    auto TILE = [&](int c, int t) {
        LDA(c, 0);
        LDB0(c);
        if (t + 1 < 18) STAGE_A(c ^ 1, t + 1, 1);
        BAR();
        MMQ0(0);
        LDB1(c);
        if (t + 1 < 18) STAGE_B(c ^ 1, t + 1, 1);
        BAR();
        MMQ1(0);
        LDA(c, 1);
        if (t + 2 < 18) STAGE_B(c, t + 2, 0);
        BAR();
        MMQ1(1);
        if (t + 2 < 18) STAGE_A(c, t + 2, 0);
        // counted drain BEFORE the ph4 barrier: t+1 fully landed, t+2.h0 flies
        if (t <= 15)      { asm volatile("s_waitcnt vmcnt(4)" ::: "memory"); }
        else if (t == 16) { asm volatile("s_waitcnt vmcnt(0)" ::: "memory"); }
        BAR();
        MMQ0(1);
    };

    // prologue: tile0 (4 halves) + B-h0(1), A-h0(1)
    STAGE_A(0, 0, 0); STAGE_A(0, 0, 1);
    STAGE_B(0, 0, 0); STAGE_B(0, 0, 1);
    STAGE_B(1, 1, 0); STAGE_A(1, 1, 0);
    asm volatile("s_waitcnt vmcnt(4)" ::: "memory");
    BAR();

#pragma unroll 1
    for (int tp = 0; tp < 18; tp += 2) {   // 9 pairs, static buffer parity
        TILE(0, tp);
        TILE(1, tp + 1);
    }
#undef MMQ0
#undef MMQ1

    // epilogue: C[co][m] + bias -> out[nimg][co][h][w]
    const int co0 = wr * 64;
    const int m0  = mblk * 224 + wc * 112;
    float bv[4][4];
#pragma unroll
    for (int f = 0; f < 4; ++f)
#pragma unroll
        for (int r = 0; r < 4; ++r)
            bv[f][r] = bias[co0 + f * 16 + (lane >> 4) * 4 + r];
#pragma unroll
    for (int g = 0; g < 7; ++g) {
        int m = m0 + g * 16 + (lane & 15);
        int hw = m - nimg * HWP;
        float* obase = out + (size_t)nimg * CO * HWP + hw;
#pragma unroll
        for (int f = 0; f < 4; ++f) {
            int co = co0 + f * 16 + (lane >> 4) * 4;
#pragma unroll
            for (int r = 0; r < 4; ++r)
                obase[(size_t)(co + r) * HWP] = acc[f][g][r] + bv[f][r];
        }
    }
}

// ---- fallback (round-1 direct conv) if ws too small ----
__global__ __launch_bounds__(256) void conv_k(
    const float* __restrict__ x, const float* __restrict__ wgt,
    const float* __restrict__ bias, float* __restrict__ out)
{
    int idx = blockIdx.x * 256 + threadIdx.x;
    int wg = idx % 14; int t = idx / 14;
    int ho = t % 56; t /= 56;
    int cog = t % 64; int n = t / 64;
    int w0 = wg * 4, co0 = cog * 4;
    float acc[4][4];
#pragma unroll
    for (int j = 0; j < 4; ++j) {
        float bj = bias[co0 + j];
#pragma unroll
        for (int p = 0; p < 4; ++p) acc[j][p] = bj;
    }
    const float* xn = x + (size_t)n * CI * HWP;
    for (int ci = 0; ci < CI; ++ci) {
        float xr[3][6];
#pragma unroll
        for (int kh = 0; kh < 3; ++kh) {
            int hi = ho + kh - 1;
            if (hi >= 0 && hi < HH) {
                const float* row = xn + ((size_t)ci * HH + hi) * WW;
                float4 cc = *reinterpret_cast<const float4*>(row + w0);
                xr[kh][1] = cc.x; xr[kh][2] = cc.y; xr[kh][3] = cc.z; xr[kh][4] = cc.w;
                xr[kh][0] = (w0 > 0) ? row[w0 - 1] : 0.0f;
                xr[kh][5] = (w0 + 4 < WW) ? row[w0 + 4] : 0.0f;
            } else {
#pragma unroll
                for (int q = 0; q < 6; ++q) xr[kh][q] = 0.0f;
            }
        }
#pragma unroll
        for (int j = 0; j < 4; ++j) {
            const float* wp = wgt + ((size_t)(co0 + j) * CI + ci) * 9;
            float wvv[9];
#pragma unroll
            for (int q = 0; q < 9; ++q) wvv[q] = wp[q];
#pragma unroll
            for (int kh = 0; kh < 3; ++kh)
#pragma unroll
                for (int kw = 0; kw < 3; ++kw)
#pragma unroll
                    for (int p = 0; p < 4; ++p)
                        acc[j][p] = fmaf(xr[kh][p + kw], wvv[kh * 3 + kw], acc[j][p]);
        }
    }
#pragma unroll
    for (int j = 0; j < 4; ++j) {
        float4 v = make_float4(acc[j][0], acc[j][1], acc[j][2], acc[j][3]);
        *reinterpret_cast<float4*>(out + (((size_t)n * CO + co0 + j) * HH + ho) * WW + w0) = v;
    }
}

extern "C" void kernel_launch(void* const* d_in, const int* in_sizes, int n_in,
                              void* d_out, int out_size, void* d_ws, size_t ws_size,
                              hipStream_t stream) {
    const float* x = (const float*)d_in[0];
    const float* w = (const float*)d_in[1];
    const float* b = (const float*)d_in[2];
    float* out = (float*)d_out;

    if (ws_size < WS_NEED) {  // safety fallback
        hipLaunchKernelGGL(conv_k, dim3(6272), dim3(256), 0, stream, x, w, b, out);
        return;
    }

    ushort* xTp = (ushort*)d_ws;
    ushort* wT  = (ushort*)((char*)d_ws + WT_OFF);

    hipLaunchKernelGGL(xform_x, dim3(32 * 49 * 4), dim3(256), 0, stream, x, xTp);
    hipLaunchKernelGGL(xform_aux, dim3(1152 + 456), dim3(256), 0, stream, w, wT, xTp);
    hipLaunchKernelGGL(gemm_conv, dim3(448), dim3(512), 0, stream,
                       xTp, wT, b, out);
}